// Round 3
// baseline (320.487 us; speedup 1.0000x reference)
//
#include <hip/hip_runtime.h>

// VectorQuantizer — bit-exact replication of the fp32 numpy reference:
//   d = sum(z*z,1)[:,None] + sum(c*c,1)[None,:] - 2.0*einsum('nc,kc->nk',z,c)
//   idx = argmin(d, axis=1)   (first occurrence)
// sums: numpy pairwise_sum n=64 (8 accumulators + fixed tree), products
// rounded separately (no contraction). einsum: AVX512 order — 16 lanes of
// chained FMA over 4 blocks of 16, then _mm512_reduce_add_ps tree.

#pragma clang fp contract(off)

#define KCODES 512
#define CDIM 64
#define HW 4096              // 64*64
#define ZQ_ELEMS 8388608     // 32*64*64*64

typedef float f2 __attribute__((ext_vector_type(2)));

__global__ __launch_bounds__(256) void vq_kernel(
    const float* __restrict__ z_e,
    const float* __restrict__ cb,
    float* __restrict__ out)
{
    __shared__ float scnorm[KCODES];
    // np.sum(cb*cb, axis=1): pairwise_sum n=64 replica (products pre-rounded)
    for (int k = (int)threadIdx.x; k < KCODES; k += 256) {
        const float* row = cb + k * CDIM;
        float r[8];
        #pragma unroll
        for (int j = 0; j < 8; ++j) r[j] = row[j] * row[j];
        #pragma unroll
        for (int i = 8; i < 64; i += 8) {
            #pragma unroll
            for (int j = 0; j < 8; ++j) r[j] = r[j] + row[i + j] * row[i + j];
        }
        scnorm[k] = ((r[0] + r[1]) + (r[2] + r[3])) + ((r[4] + r[5]) + (r[6] + r[7]));
    }
    __syncthreads();

    // block covers 512 consecutive points (same b since 512 | 4096)
    const int n0 = (int)blockIdx.x * 512;
    const int b = n0 / HW;
    const int hwbase = (n0 % HW) + (int)threadIdx.x * 2;
    const float* zp = z_e + (size_t)b * CDIM * HW + hwbase;

    // 2 points per thread, packed into float2 vectors
    f2 zz[CDIM];
    #pragma unroll
    for (int c = 0; c < CDIM; ++c) {
        float2 v = *(const float2*)(zp + (size_t)c * HW);
        f2 t; t.x = v.x; t.y = v.y;
        zz[c] = t;
    }

    // np.sum(z*z, axis=1): same pairwise replica, both points at once
    f2 sz;
    {
        f2 r[8];
        #pragma unroll
        for (int j = 0; j < 8; ++j) r[j] = zz[j] * zz[j];
        #pragma unroll
        for (int i = 8; i < 64; i += 8) {
            #pragma unroll
            for (int j = 0; j < 8; ++j) r[j] = r[j] + zz[i + j] * zz[i + j];
        }
        sz = ((r[0] + r[1]) + (r[2] + r[3])) + ((r[4] + r[5]) + (r[6] + r[7]));
    }

    f2 best; best.x = 3.4e38f; best.y = 3.4e38f;
    int ix = 0, iy = 0;

    for (int k = 0; k < KCODES; ++k) {
        const float* ck = cb + k * CDIM;   // wave-uniform -> scalar loads

        // einsum inner loop, AVX512 (vstep=16, one x4 block), chained FMA:
        // v[l] = fma(z[l],c[l], fma(z[16+l],c[16+l], fma(z[32+l],c[32+l],
        //        fma(z[48+l],c[48+l], 0))))
        f2 v[16];
        #pragma unroll
        for (int l = 0; l < 16; ++l) {
            f2 c0; c0.x = ck[l];      c0.y = c0.x;
            f2 c1; c1.x = ck[16 + l]; c1.y = c1.x;
            f2 c2; c2.x = ck[32 + l]; c2.y = c2.x;
            f2 c3; c3.x = ck[48 + l]; c3.y = c3.x;
            f2 zero; zero.x = 0.f; zero.y = 0.f;
            v[l] = __builtin_elementwise_fma(zz[l], c0,
                     __builtin_elementwise_fma(zz[16 + l], c1,
                       __builtin_elementwise_fma(zz[32 + l], c2,
                         __builtin_elementwise_fma(zz[48 + l], c3, zero))));
        }
        // _mm512_reduce_add_ps tree: e_l = v_l + v_{l+8}; f_l = e_l + e_{l+4};
        // total = (f0+f2) + (f1+f3)
        f2 e0 = v[0] + v[8],  e1 = v[1] + v[9],  e2 = v[2] + v[10], e3 = v[3] + v[11];
        f2 e4 = v[4] + v[12], e5 = v[5] + v[13], e6 = v[6] + v[14], e7 = v[7] + v[15];
        f2 f0 = e0 + e4, f1 = e1 + e5, fx2 = e2 + e6, fx3 = e3 + e7;
        f2 dot = (f0 + fx2) + (f1 + fx3);

        float sckv = scnorm[k];
        f2 sck; sck.x = sckv; sck.y = sckv;
        f2 A = sz + sck;                    // fl(sz + sc_k)
        f2 m2; m2.x = -2.f; m2.y = -2.f;
        f2 d = A + dot * m2;                // fl(A - 2*dot)  (2*dot exact)

        if (d.x < best.x) { best.x = d.x; ix = k; }   // strict <: first occurrence
        if (d.y < best.y) { best.y = d.y; iy = k; }
    }

    // indices (as float32, second output region)
    const int n = n0 + (int)threadIdx.x * 2;
    out[ZQ_ELEMS + n]     = (float)ix;
    out[ZQ_ELEMS + n + 1] = (float)iy;

    // z_q gather: out[b][c][hw] = cb[idx][c], coalesced float2 stores
    const float* rx = cb + (size_t)ix * CDIM;
    const float* ry = cb + (size_t)iy * CDIM;
    float* op = out + (size_t)b * CDIM * HW + hwbase;
    #pragma unroll
    for (int c = 0; c < CDIM; ++c) {
        float2 w; w.x = rx[c]; w.y = ry[c];
        *(float2*)(op + (size_t)c * HW) = w;
    }
}

extern "C" void kernel_launch(void* const* d_in, const int* in_sizes, int n_in,
                              void* d_out, int out_size, void* d_ws, size_t ws_size,
                              hipStream_t stream) {
    const float* z_e = (const float*)d_in[0];
    const float* cb  = (const float*)d_in[1];
    float* out = (float*)d_out;
    vq_kernel<<<dim3(256), dim3(256), 0, stream>>>(z_e, cb, out);
}

// Round 4
// 238.291 us; speedup vs baseline: 1.3449x; 1.3449x over previous
//
#include <hip/hip_runtime.h>

// VectorQuantizer — bit-exact replication of the fp32 numpy reference, with
// the k-argmin parallelized across 4 waves per 64-point tile.
//   d = sum(z*z,1)[:,None] + sum(c*c,1)[None,:] - 2.0*einsum('nc,kc->nk',z,c)
// sums: numpy pairwise_sum n=64 (8 accumulators + fixed tree), products
// rounded separately. einsum: AVX512 order — chained FMA depth 4 over blocks
// of 16 lanes, then _mm512_reduce_add_ps tree. All orders preserved exactly;
// argmin combined across disjoint increasing k-ranges with strict < (first-
// occurrence semantics preserved).

#pragma clang fp contract(off)

#define KCODES 512
#define CDIM 64
#define HW 4096              // 64*64
#define ZQ_ELEMS 8388608     // 32*64*64*64

__global__ __launch_bounds__(256, 4) void vq_kernel(
    const float* __restrict__ z_e,
    const float* __restrict__ cb,
    float* __restrict__ out)
{
    __shared__ float cnorm[KCODES];
    __shared__ float dcand[256];
    __shared__ int   kcand[256];

    // np.sum(cb*cb, axis=1): pairwise_sum n=64 replica (products pre-rounded)
    for (int k = (int)threadIdx.x; k < KCODES; k += 256) {
        const float* row = cb + k * CDIM;
        float r[8];
        #pragma unroll
        for (int j = 0; j < 8; ++j) r[j] = row[j] * row[j];
        #pragma unroll
        for (int i = 8; i < 64; i += 8) {
            #pragma unroll
            for (int j = 0; j < 8; ++j) r[j] = r[j] + row[i + j] * row[i + j];
        }
        cnorm[k] = ((r[0] + r[1]) + (r[2] + r[3])) + ((r[4] + r[5]) + (r[6] + r[7]));
    }

    // block = 64 consecutive points; wave g covers k in [128g, 128g+128)
    const int lane = (int)threadIdx.x & 63;
    const int g = __builtin_amdgcn_readfirstlane((int)threadIdx.x >> 6); // wave-uniform
    const int n0 = (int)blockIdx.x * 64;
    const int b = n0 / HW;
    const int hw0 = n0 % HW;
    const float* zp = z_e + (size_t)b * CDIM * HW + hw0 + lane;

    // one point per lane: z vector in 64 VGPRs (coalesced 4B/lane loads)
    float z[CDIM];
    #pragma unroll
    for (int c = 0; c < CDIM; ++c) z[c] = zp[(size_t)c * HW];

    // np.sum(z*z, axis=1): same pairwise replica
    float sz;
    {
        float r[8];
        #pragma unroll
        for (int j = 0; j < 8; ++j) r[j] = z[j] * z[j];
        #pragma unroll
        for (int i = 8; i < 64; i += 8) {
            #pragma unroll
            for (int j = 0; j < 8; ++j) r[j] = r[j] + z[i + j] * z[i + j];
        }
        sz = ((r[0] + r[1]) + (r[2] + r[3])) + ((r[4] + r[5]) + (r[6] + r[7]));
    }

    __syncthreads();

    float best = 3.4e38f;
    int bk = 0;
    const int k0 = g * 128;

    for (int i = 0; i < 128; ++i) {
        const int k = k0 + i;                 // wave-uniform -> s_load path
        const float* ck = cb + k * CDIM;

        // einsum AVX512 order: v[l] = fma(z[l],c[l], fma(z[16+l],c[16+l],
        //   fma(z[32+l],c[32+l], fma(z[48+l],c[48+l], 0))))
        float v[16];
        #pragma unroll
        for (int l = 0; l < 16; ++l) {
            v[l] = fmaf(z[l], ck[l],
                     fmaf(z[16 + l], ck[16 + l],
                       fmaf(z[32 + l], ck[32 + l],
                         fmaf(z[48 + l], ck[48 + l], 0.f))));
        }
        // _mm512_reduce_add_ps tree
        float e0 = v[0] + v[8],  e1 = v[1] + v[9],  e2 = v[2] + v[10], e3 = v[3] + v[11];
        float e4 = v[4] + v[12], e5 = v[5] + v[13], e6 = v[6] + v[14], e7 = v[7] + v[15];
        float f0 = e0 + e4, f1 = e1 + e5, f2 = e2 + e6, f3 = e3 + e7;
        float dot = (f0 + f2) + (f1 + f3);

        float A = sz + cnorm[k];              // fl(sz + sc_k)
        float d = A + dot * -2.f;             // fl(A - 2*dot), 2*dot exact

        if (d < best) { best = d; bk = k; }   // strict <: first occurrence
    }

    dcand[g * 64 + lane] = best;
    kcand[g * 64 + lane] = bk;
    __syncthreads();

    // combine 4 candidates per point (increasing k-range order -> strict <
    // preserves first-occurrence). All waves compute it (no extra sync).
    float bd = dcand[lane];
    int bi = kcand[lane];
    #pragma unroll
    for (int gg = 1; gg < 4; ++gg) {
        float d2 = dcand[gg * 64 + lane];
        int   k2 = kcand[gg * 64 + lane];
        if (d2 < bd) { bd = d2; bi = k2; }
    }

    // indices (as float32, second output region) — wave 0 only
    if (g == 0) out[ZQ_ELEMS + n0 + lane] = (float)bi;

    // z_q: wave g writes channels [16g, 16g+16); coalesced 4B/lane stores
    const float* row = cb + (size_t)bi * CDIM;
    float* op = out + (size_t)b * CDIM * HW + hw0 + lane;
    #pragma unroll
    for (int c = 0; c < 16; ++c) {
        const int ch = g * 16 + c;
        op[(size_t)ch * HW] = row[ch];
    }
}

extern "C" void kernel_launch(void* const* d_in, const int* in_sizes, int n_in,
                              void* d_out, int out_size, void* d_ws, size_t ws_size,
                              hipStream_t stream) {
    const float* z_e = (const float*)d_in[0];
    const float* cb  = (const float*)d_in[1];
    float* out = (float*)d_out;
    vq_kernel<<<dim3(2048), dim3(256), 0, stream>>>(z_e, cb, out);
}

// Round 5
// 197.741 us; speedup vs baseline: 1.6207x; 1.2051x over previous
//
#include <hip/hip_runtime.h>

// VectorQuantizer — bit-exact replication of the fp32 numpy reference.
//   d = sum(z*z,1)[:,None] + sum(c*c,1)[None,:] - 2.0*einsum('nc,kc->nk',z,c)
// sums: numpy pairwise_sum n=64 (8 accumulators + fixed tree), products
// rounded separately (contract off). einsum: AVX512 order — chained FMA
// depth 4 over blocks of 16, then _mm512_reduce_add_ps tree.
//
// Structure: 2 points/lane packed in f2 (v_pk_fma_f32: 2 MACs/instr, proven
// bit-exact in round 3) x 4-wave k-split (wave g covers k in [128g,128g+128),
// proven in round 4). Block = 128 points x 512 codes; 1024 blocks.
// Argmin combined across ascending disjoint k-ranges with strict < (first-
// occurrence preserved). IEEE add is commutative, so packed halves are exact.

#pragma clang fp contract(off)

#define KCODES 512
#define CDIM 64
#define HW 4096              // 64*64
#define ZQ_ELEMS 8388608     // 32*64*64*64

typedef float f2 __attribute__((ext_vector_type(2)));

__global__ __launch_bounds__(256, 3) void vq_kernel(
    const float* __restrict__ z_e,
    const float* __restrict__ cb,
    float* __restrict__ out)
{
    __shared__ float cnorm[KCODES];
    __shared__ float dcand[4 * 128];
    __shared__ int   kcand[4 * 128];

    // np.sum(cb*cb, axis=1): pairwise_sum n=64 replica (products pre-rounded)
    for (int k = (int)threadIdx.x; k < KCODES; k += 256) {
        const float* row = cb + k * CDIM;
        float r[8];
        #pragma unroll
        for (int j = 0; j < 8; ++j) r[j] = row[j] * row[j];
        #pragma unroll
        for (int i = 8; i < 64; i += 8) {
            #pragma unroll
            for (int j = 0; j < 8; ++j) r[j] = r[j] + row[i + j] * row[i + j];
        }
        cnorm[k] = ((r[0] + r[1]) + (r[2] + r[3])) + ((r[4] + r[5]) + (r[6] + r[7]));
    }

    // block = 128 consecutive points; wave g covers k in [128g, 128g+128)
    const int lane = (int)threadIdx.x & 63;
    const int g = __builtin_amdgcn_readfirstlane((int)threadIdx.x >> 6);
    const int n0 = (int)blockIdx.x * 128;
    const int b = n0 / HW;
    const int hw0 = n0 % HW;
    const float* zp = z_e + (size_t)b * CDIM * HW + hw0 + lane * 2;

    // 2 points per lane, packed f2 (coalesced float2 loads)
    f2 zz[CDIM];
    #pragma unroll
    for (int c = 0; c < CDIM; ++c) {
        float2 v = *(const float2*)(zp + (size_t)c * HW);
        f2 t; t.x = v.x; t.y = v.y;
        zz[c] = t;
    }

    // np.sum(z*z, axis=1): pairwise replica, both points at once
    f2 sz;
    {
        f2 r[8];
        #pragma unroll
        for (int j = 0; j < 8; ++j) r[j] = zz[j] * zz[j];
        #pragma unroll
        for (int i = 8; i < 64; i += 8) {
            #pragma unroll
            for (int j = 0; j < 8; ++j) r[j] = r[j] + zz[i + j] * zz[i + j];
        }
        sz = ((r[0] + r[1]) + (r[2] + r[3])) + ((r[4] + r[5]) + (r[6] + r[7]));
    }

    __syncthreads();

    f2 best; best.x = 3.4e38f; best.y = 3.4e38f;
    int ix = 0, iy = 0;
    const int k0 = g * 128;

    for (int i = 0; i < 128; ++i) {
        const int k = k0 + i;                  // wave-uniform -> s_load path
        const float* ck = cb + k * CDIM;

        // einsum AVX512 order: v[l] = fma(z[l],c[l], fma(z[16+l],c[16+l],
        //   fma(z[32+l],c[32+l], fma(z[48+l],c[48+l], 0))))
        f2 v[16];
        #pragma unroll
        for (int l = 0; l < 16; ++l) {
            f2 c0; c0.x = ck[l];      c0.y = c0.x;
            f2 c1; c1.x = ck[16 + l]; c1.y = c1.x;
            f2 c2; c2.x = ck[32 + l]; c2.y = c2.x;
            f2 c3; c3.x = ck[48 + l]; c3.y = c3.x;
            f2 zero; zero.x = 0.f; zero.y = 0.f;
            v[l] = __builtin_elementwise_fma(zz[l], c0,
                     __builtin_elementwise_fma(zz[16 + l], c1,
                       __builtin_elementwise_fma(zz[32 + l], c2,
                         __builtin_elementwise_fma(zz[48 + l], c3, zero))));
        }
        // _mm512_reduce_add_ps tree
        f2 e0 = v[0] + v[8],  e1 = v[1] + v[9],  e2 = v[2] + v[10], e3 = v[3] + v[11];
        f2 e4 = v[4] + v[12], e5 = v[5] + v[13], e6 = v[6] + v[14], e7 = v[7] + v[15];
        f2 f0 = e0 + e4, f1 = e1 + e5, fx2 = e2 + e6, fx3 = e3 + e7;
        f2 dot = (f0 + fx2) + (f1 + fx3);

        float sckv = cnorm[k];                 // LDS broadcast
        f2 sck; sck.x = sckv; sck.y = sckv;
        f2 A = sz + sck;                       // fl(sz + sc_k)
        f2 m2; m2.x = -2.f; m2.y = -2.f;
        f2 d = A + dot * m2;                   // fl(A - 2*dot), 2*dot exact

        if (d.x < best.x) { best.x = d.x; ix = k; }   // strict <: first occurrence
        if (d.y < best.y) { best.y = d.y; iy = k; }
    }

    // publish per-wave candidates (points 2*lane, 2*lane+1)
    dcand[g * 128 + lane * 2]     = best.x;
    dcand[g * 128 + lane * 2 + 1] = best.y;
    kcand[g * 128 + lane * 2]     = ix;
    kcand[g * 128 + lane * 2 + 1] = iy;
    __syncthreads();

    // combine over ascending k-ranges (strict < keeps first occurrence);
    // every thread resolves its own 2 points (2-way LDS aliasing = free)
    float bdx = dcand[lane * 2],     bdy = dcand[lane * 2 + 1];
    int   bix = kcand[lane * 2],     biy = kcand[lane * 2 + 1];
    #pragma unroll
    for (int gg = 1; gg < 4; ++gg) {
        float dx2 = dcand[gg * 128 + lane * 2];
        float dy2 = dcand[gg * 128 + lane * 2 + 1];
        int   kx2 = kcand[gg * 128 + lane * 2];
        int   ky2 = kcand[gg * 128 + lane * 2 + 1];
        if (dx2 < bdx) { bdx = dx2; bix = kx2; }
        if (dy2 < bdy) { bdy = dy2; biy = ky2; }
    }

    // indices (as float32, second output region) — wave 0 only
    if (g == 0) {
        float2 w; w.x = (float)bix; w.y = (float)biy;
        *(float2*)(out + ZQ_ELEMS + n0 + lane * 2) = w;
    }

    // z_q: wave g writes channels [16g, 16g+16); coalesced float2 stores
    const float* rx = cb + (size_t)bix * CDIM;
    const float* ry = cb + (size_t)biy * CDIM;
    float* op = out + (size_t)b * CDIM * HW + hw0 + lane * 2;
    #pragma unroll
    for (int c = 0; c < 16; ++c) {
        const int ch = g * 16 + c;
        float2 w; w.x = rx[ch]; w.y = ry[ch];
        *(float2*)(op + (size_t)ch * HW) = w;
    }
}

extern "C" void kernel_launch(void* const* d_in, const int* in_sizes, int n_in,
                              void* d_out, int out_size, void* d_ws, size_t ws_size,
                              hipStream_t stream) {
    const float* z_e = (const float*)d_in[0];
    const float* cb  = (const float*)d_in[1];
    float* out = (float*)d_out;
    vq_kernel<<<dim3(1024), dim3(256), 0, stream>>>(z_e, cb, out);
}